// Round 7
// baseline (34.719 us; speedup 1.0000x reference)
//
#include <hip/hip_runtime.h>

// YOLO loss: preds/targets (N,7,7,2*(5+20)) fp32 -> scalar fp32.
// S=7, B=2, C=20, LAMBDA_NOOBJ=0.5, EPS=1e-9, divide by N at the end.
//
// R7: load ONLY the used bytes. Per cell (50 floats) the loss reads just 28
// pred floats (ch0-3, 25-28, 30-49) and 30 target floats (ch0-4, 25-29,
// 30-49). global_load_lds takes PER-LANE global addresses (guide m173), so
// we gather the used float4 chunks of each 2-cell pair (16-chunk pattern +
// 1 extra word for t.ch4 of the even cell): 17KB per 64-cell tile vs 25.6KB
// naive = 66% of per-CU ingest. Chunk slots are XOR-swizzled (s ^ (q&15))
// via pre-swizzled global addresses, LDS stays linear -> compute-side
// ds_reads spread across banks (<=4-way).
// Retained: persistent 1-wave blocks, double-buffer, counted vmcnt (R5/R6);
// partials to d_ws + tiny final kernel (R3: no same-address atomics);
// coalesced/gathered staging only (R4: scattered per-thread loads TA-split).
//
// Pair layout (pair = 2 cells = 100 floats; cell A = f0-49, B = f50-99):
// slot s -> float4 #kf(s), kf = {0, 6,7,8,9,10,11,12,13, 18,19, 20..24}
//  s0: f0-3   (A box0 xywh)          s8:  f52-55 (B ch2-5)
//  s1: f24-27 (A ch24-27)            s9:  f72-75 (B ch22-25)
//  s2: f28-31 (A ch28-31)            s10: f76-79 (B ch26-29)
//  s3-s6: f32-47 (A cls)             s11-s15: f80-99 (B cls)
//  s7: f48-51 (A cls18,19; B ch0,1)  extra: f4 (A t-conf, targets only)

#define NPC 50
#define CPT 64                  // cells per tile
#define TPB 64                  // 1 wave per block
#define TILE_F (CPT * NPC)      // 3200 floats per tensor per tile
#define LP_F 2048               // preds region: 32 pairs x 16 slots x 4
#define LT_F 2048
#define LE_F 64                 // t.ch4 extras
#define BUF_F (LP_F + LT_F + LE_F)   // 4160 floats = 16.25 KB per buffer

typedef const __attribute__((address_space(1))) void gvoid_t;
typedef __attribute__((address_space(3))) void lvoid_t;

__device__ __forceinline__ float iou_xywh(float px, float py, float pw, float ph,
                                          float tx, float ty, float tw, float th) {
    float ax1 = px - pw * 0.5f, ay1 = py - ph * 0.5f;
    float ax2 = px + pw * 0.5f, ay2 = py + ph * 0.5f;
    float bx1 = tx - tw * 0.5f, by1 = ty - th * 0.5f;
    float bx2 = tx + tw * 0.5f, by2 = ty + th * 0.5f;
    float iw = fmaxf(fminf(ax2, bx2) - fmaxf(ax1, bx1), 0.0f);
    float ih = fmaxf(fminf(ay2, by2) - fmaxf(ay1, by1), 0.0f);
    float inter = iw * ih;
    float uni = pw * ph + tw * th - inter;
    return inter / (uni + 1e-9f);
}

// Full per-cell loss from global memory -- remainder fallback only.
__device__ __forceinline__ float cell_loss(const float2* __restrict__ cp2,
                                           const float2* __restrict__ ct2) {
    float2 p01 = cp2[0], p23 = cp2[1];
    float2 t01 = ct2[0], t23 = ct2[1], t4_ = ct2[2];
    float2 pA = cp2[12], pB = cp2[13], pC = cp2[14];
    float2 tA = ct2[12], tB = ct2[13], tC = ct2[14];

    float iou0 = iou_xywh(p01.x, p01.y, p23.x, p23.y, t01.x, t01.y, t23.x, t23.y);
    float iou1 = iou_xywh(pA.y, pB.x, pB.y, pC.x, tA.y, tB.x, tB.y, tC.x);
    int best = (iou1 > iou0) ? 1 : 0;
    bool has_obj = (t4_.x > 0.0f) || (tC.y > 0.0f);

    float dx, dy;
    if (best == 0) { dx = p01.x - t01.x; dy = p01.y - t01.y; }
    else           { dx = pA.y - tA.y;   dy = pB.x - tB.x;   }
    float cell = has_obj ? (dx * dx + dy * dy) : 0.0f;

    float csum = 0.0f, bv = -1e30f, pg = 0.0f;
    #pragma unroll
    for (int j = 0; j < 10; ++j) {
        float2 tv = ct2[15 + j];
        float2 pv = cp2[15 + j];
        float d0 = pv.x - tv.x, d1 = pv.y - tv.y;
        csum += d0 * d0 + d1 * d1;
        if (tv.x > bv) { bv = tv.x; pg = pv.x; }
        if (tv.y > bv) { bv = tv.y; pg = pv.y; }
    }
    cell += csum;

    float f = pg - 1.0f, f2 = f * f;
    float e0 = iou0 * iou0 * f2, e1 = iou1 * iou1 * f2;
    cell += (best == 0) ? e0 : 0.5f * e0;
    cell += (best == 1) ? e1 : 0.5f * e1;
    return cell;
}

__global__ __launch_bounds__(TPB) void yolo_cell_kernel(
        const float* __restrict__ preds,
        const float* __restrict__ targets,
        float* __restrict__ part,
        int ncells, int nb) {
    __shared__ float lbuf[2][BUF_F];   // 2 x 16.25 KB = 32.5 KB -> 4 blocks/CU

    const int lane = threadIdx.x;
    const int bid = blockIdx.x;
    const int ntiles = ncells / CPT;

    // Per-lane gather offsets (bytes, rel. tile base). Instr i covers pairs
    // 4i..4i+3: lane>>4 = pair-in-group, lane&15 = LDS slot position sigma.
    // Chunk stored at sigma is s = sigma ^ (q&15) (bank swizzle, applied by
    // permuting the GLOBAL address; LDS dest stays linear base + lane*16).
    unsigned goff[8];
    {
        const int pgrp = lane >> 4;
        const int sig = lane & 15;
        #pragma unroll
        for (int i = 0; i < 8; ++i) {
            const int q = 4 * i + pgrp;
            const int s = sig ^ (q & 15);
            const int kf = (s == 0) ? 0 : ((s <= 8) ? s + 5 : s + 9);
            goff[i] = (unsigned)(q * 400 + kf * 16);
        }
    }
    const unsigned eoff = (unsigned)((lane & 31) * 400 + 16);   // t f4 (A ch4)

    auto stage = [&](int b, int t) {
        const char* pb = (const char*)(preds + (long long)t * TILE_F);
        const char* tb = (const char*)(targets + (long long)t * TILE_F);
        float* lp = lbuf[b];
        float* lt = lbuf[b] + LP_F;
        float* le = lbuf[b] + LP_F + LT_F;
        #pragma unroll
        for (int i = 0; i < 8; ++i)
            __builtin_amdgcn_global_load_lds((gvoid_t*)(pb + goff[i]),
                                             (lvoid_t*)(lp + i * 256), 16, 0, 0);
        #pragma unroll
        for (int i = 0; i < 8; ++i)
            __builtin_amdgcn_global_load_lds((gvoid_t*)(tb + goff[i]),
                                             (lvoid_t*)(lt + i * 256), 16, 0, 0);
        __builtin_amdgcn_global_load_lds((gvoid_t*)(tb + eoff),
                                         (lvoid_t*)le, 4, 0, 0);
    };  // 17 loads per tile

    float acc = 0.0f;

    if (bid < ntiles) stage(0, bid);
    int b = 0;
    for (int t = bid; t < ntiles; t += nb) {
        const int tn = t + nb;
        if (tn < ntiles) {
            stage(b ^ 1, tn);
            // wait for tile t's 17 loads; tn's 17 stay in flight
            asm volatile("s_waitcnt vmcnt(17)" ::: "memory");
        } else {
            asm volatile("s_waitcnt vmcnt(0)" ::: "memory");
        }
        __builtin_amdgcn_sched_barrier(0);

        const float* lp = lbuf[b];
        const float* lt = lbuf[b] + LP_F;
        const float* le = lbuf[b] + LP_F + LT_F;
        const int q = lane >> 1;           // pair index 0..31
        const int q15 = q & 15;
        const float* lpq = lp + q * 64;
        const float* ltq = lt + q * 64;
#define S4(base, s) (*(const float4*)((base) + (((s) ^ q15) * 4)))

        float csum = 0.0f, bv = -1e30f, pg = 0.0f;
        auto cls4 = [&](float4 pv, float4 tv) {
            float d;
            d = pv.x - tv.x; csum += d * d; if (tv.x > bv) { bv = tv.x; pg = pv.x; }
            d = pv.y - tv.y; csum += d * d; if (tv.y > bv) { bv = tv.y; pg = pv.y; }
            d = pv.z - tv.z; csum += d * d; if (tv.z > bv) { bv = tv.z; pg = pv.z; }
            d = pv.w - tv.w; csum += d * d; if (tv.w > bv) { bv = tv.w; pg = pv.w; }
        };
        auto cls1 = [&](float p, float t_) {
            float d = p - t_; csum += d * d; if (t_ > bv) { bv = t_; pg = p; }
        };

        float iou0, iou1, dx, dy;
        bool best, has_obj;
        if (!(lane & 1)) {
            // ---- cell A (f0-49) ----
            float4 P0 = S4(lpq, 0), P1 = S4(lpq, 1), P2 = S4(lpq, 2);
            float4 T0 = S4(ltq, 0), T1 = S4(ltq, 1), T2 = S4(ltq, 2);
            iou0 = iou_xywh(P0.x, P0.y, P0.z, P0.w, T0.x, T0.y, T0.z, T0.w);
            iou1 = iou_xywh(P1.y, P1.z, P1.w, P2.x, T1.y, T1.z, T1.w, T2.x);
            has_obj = (le[q] > 0.0f) || (T2.y > 0.0f);     // t ch4, t ch29
            best = (iou1 > iou0);
            dx = best ? P1.y - T1.y : P0.x - T0.x;
            dy = best ? P1.z - T1.z : P0.y - T0.y;
            // cls ch30..49 in order: f30,f31, f32-47, f48,f49
            cls1(P2.z, T2.z); cls1(P2.w, T2.w);
            cls4(S4(lpq, 3), S4(ltq, 3));
            cls4(S4(lpq, 4), S4(ltq, 4));
            cls4(S4(lpq, 5), S4(ltq, 5));
            cls4(S4(lpq, 6), S4(ltq, 6));
            float4 P7 = S4(lpq, 7), T7 = S4(ltq, 7);
            cls1(P7.x, T7.x); cls1(P7.y, T7.y);
        } else {
            // ---- cell B (f50-99) ----
            float4 P7 = S4(lpq, 7), P8 = S4(lpq, 8), P9 = S4(lpq, 9), PA = S4(lpq, 10);
            float4 T7 = S4(ltq, 7), T8 = S4(ltq, 8), T9 = S4(ltq, 9), TA = S4(ltq, 10);
            iou0 = iou_xywh(P7.z, P7.w, P8.x, P8.y, T7.z, T7.w, T8.x, T8.y);
            iou1 = iou_xywh(P9.w, PA.x, PA.y, PA.z, T9.w, TA.x, TA.y, TA.z);
            has_obj = (T8.z > 0.0f) || (TA.w > 0.0f);      // t ch4(f54), t ch29(f79)
            best = (iou1 > iou0);
            dx = best ? P9.w - T9.w : P7.z - T7.z;
            dy = best ? PA.x - TA.x : P7.w - T7.w;
            // cls ch30..49 = f80-99 in order
            cls4(S4(lpq, 11), S4(ltq, 11));
            cls4(S4(lpq, 12), S4(ltq, 12));
            cls4(S4(lpq, 13), S4(ltq, 13));
            cls4(S4(lpq, 14), S4(ltq, 14));
            cls4(S4(lpq, 15), S4(ltq, 15));
        }
#undef S4
        float cell = (has_obj ? dx * dx + dy * dy : 0.0f) + csum;
        float f = pg - 1.0f, f2 = f * f;
        float e0 = iou0 * iou0 * f2, e1 = iou1 * iou1 * f2;
        cell += best ? (0.5f * e0 + e1) : (e0 + 0.5f * e1);
        acc += cell;

        b ^= 1;
    }

    // ---- remainder cells (ncells % 64; zero for this problem size) ----
    const int rem0 = ntiles * CPT;
    if (rem0 < ncells && bid == nb - 1) {
        for (int i = rem0 + lane; i < ncells; i += TPB) {
            const float2* cp2 = (const float2*)(preds + (long long)i * NPC);
            const float2* ct2 = (const float2*)(targets + (long long)i * NPC);
            acc += cell_loss(cp2, ct2);
        }
    }

    // ---- wave reduction, one plain store per block (no atomics) ----
    #pragma unroll
    for (int off = 32; off >= 1; off >>= 1) acc += __shfl_down(acc, off);
    if (lane == 0) part[bid] = acc;
}

__global__ __launch_bounds__(256) void yolo_final_kernel(
        const float* __restrict__ part, float* __restrict__ out,
        int nblk, float invN) {
    __shared__ float wsum[4];
    const int tid = threadIdx.x;
    float s = 0.0f;
    for (int i = tid; i < nblk; i += 256) s += part[i];
    #pragma unroll
    for (int off = 32; off >= 1; off >>= 1) s += __shfl_down(s, off);
    if ((tid & 63) == 0) wsum[tid >> 6] = s;
    __syncthreads();
    if (tid == 0) {
        out[0] = (wsum[0] + wsum[1] + wsum[2] + wsum[3]) * invN;
    }
}

extern "C" void kernel_launch(void* const* d_in, const int* in_sizes, int n_in,
                              void* d_out, int out_size, void* d_ws, size_t ws_size,
                              hipStream_t stream) {
    const float* preds = (const float*)d_in[0];
    const float* targets = (const float*)d_in[1];
    float* out = (float*)d_out;
    float* part = (float*)d_ws;                 // nb floats of scratch

    const int ncells = in_sizes[0] / NPC;       // N*S*S = 401408
    const int N = ncells / 49;                  // S*S = 49
    const int nb = 1024;                        // 4 blocks/CU x 256 CU

    yolo_cell_kernel<<<nb, TPB, 0, stream>>>(preds, targets, part, ncells, nb);
    yolo_final_kernel<<<1, 256, 0, stream>>>(part, out, nb, 1.0f / (float)N);
}

// Round 8
// 31.066 us; speedup vs baseline: 1.1176x; 1.1176x over previous
//
#include <hip/hip_runtime.h>

// YOLO loss: preds/targets (N,7,7,2*(5+20)) fp32 -> scalar fp32.
// S=7, B=2, C=20, LAMBDA_NOOBJ=0.5, EPS=1e-9, divide by N at the end.
//
// R8 = revert to R5, the measured-best structure (31.1us). Session evidence:
//  - R3: same-address atomicAdd chain = ~25us serialized overhead -> partials
//    to d_ws + tiny final kernel (kept).
//  - R4: per-thread scattered loads TA-split (~100 lines/instr), 2 TB/s cap
//    -> coalesced global_load_lds staging only (kept).
//  - R5: persistent 1-wave blocks + dbuf + counted vmcnt = 31.1us (BEST).
//  - R6: 2x streams/CU (6 blocks/CU, 0 bank conflicts): NULL -> not latency-
//    or conflict-bound.
//  - R7: gather only used bytes (66% of requests): NULL, FETCH unchanged ->
//    delivery is line-granular; fabric/L3 aggregate BW (~5.7-5.9 TB/s) is
//    the wall. This kernel sits at ~90% of the m13 copy ceiling.

#define NPC 50            // floats per cell per tensor
#define CPT 64            // cells per tile
#define TPB 64            // 1 wave per block
#define TILE_F (CPT * NPC)   // 3200 floats per tensor per tile

typedef const __attribute__((address_space(1))) void gvoid_t;
typedef __attribute__((address_space(3))) void lvoid_t;

__device__ __forceinline__ float iou_xywh(float px, float py, float pw, float ph,
                                          float tx, float ty, float tw, float th) {
    float ax1 = px - pw * 0.5f, ay1 = py - ph * 0.5f;
    float ax2 = px + pw * 0.5f, ay2 = py + ph * 0.5f;
    float bx1 = tx - tw * 0.5f, by1 = ty - th * 0.5f;
    float bx2 = tx + tw * 0.5f, by2 = ty + th * 0.5f;
    float iw = fmaxf(fminf(ax2, bx2) - fmaxf(ax1, bx1), 0.0f);
    float ih = fmaxf(fminf(ay2, by2) - fmaxf(ay1, by1), 0.0f);
    float inter = iw * ih;
    float uni = pw * ph + tw * th - inter;
    return inter / (uni + 1e-9f);
}

// Full per-cell loss. cp2/ct2 point at one cell's 50 floats (8B-aligned).
__device__ __forceinline__ float cell_loss(const float2* __restrict__ cp2,
                                           const float2* __restrict__ ct2) {
    float2 p01 = cp2[0];            // p0,p1
    float2 p23 = cp2[1];            // p2,p3
    float2 t01 = ct2[0];
    float2 t23 = ct2[1];
    float2 t4_ = ct2[2];            // t4, t5(unused)
    float2 pA = cp2[12];            // p24(unused), p25
    float2 pB = cp2[13];            // p26, p27
    float2 pC = cp2[14];            // p28, p29(unused)
    float2 tA = ct2[12];
    float2 tB = ct2[13];
    float2 tC = ct2[14];

    float iou0 = iou_xywh(p01.x, p01.y, p23.x, p23.y,
                          t01.x, t01.y, t23.x, t23.y);
    float iou1 = iou_xywh(pA.y, pB.x, pB.y, pC.x,
                          tA.y, tB.x, tB.y, tC.x);
    int best = (iou1 > iou0) ? 1 : 0;   // argmax, first-max tie-break
    bool has_obj = (t4_.x > 0.0f) || (tC.y > 0.0f);

    float dx, dy;
    if (best == 0) { dx = p01.x - t01.x; dy = p01.y - t01.y; }
    else           { dx = pA.y - tA.y;   dy = pB.x - tB.x;   }
    float cell = has_obj ? (dx * dx + dy * dy) : 0.0f;

    // classes of b = B-1 = 1: channels [30..49] = float2 idx [15..24]
    float csum = 0.0f;
    float bv = -1e30f;   // running max of tc (strict > keeps first max)
    float pg = 0.0f;     // pc at argmax(tc)
    #pragma unroll
    for (int j = 0; j < 10; ++j) {
        float2 tv = ct2[15 + j];
        float2 pv = cp2[15 + j];
        float d0 = pv.x - tv.x;
        float d1 = pv.y - tv.y;
        csum += d0 * d0 + d1 * d1;
        if (tv.x > bv) { bv = tv.x; pg = pv.x; }
        if (tv.y > bv) { bv = tv.y; pg = pv.y; }
    }
    cell += csum;

    // conf term: (iou_b * p_gt - iou_b)^2, weight 1 at best else 0.5
    float f = pg - 1.0f;
    float f2 = f * f;
    float e0 = iou0 * iou0 * f2;
    float e1 = iou1 * iou1 * f2;
    cell += (best == 0) ? e0 : 0.5f * e0;
    cell += (best == 1) ? e1 : 0.5f * e1;
    return cell;
}

__global__ __launch_bounds__(TPB) void yolo_cell_kernel(
        const float* __restrict__ preds,
        const float* __restrict__ targets,
        float* __restrict__ part,
        int ncells, int nb) {
    __shared__ float lbuf[2][2 * TILE_F];   // [buf][preds|targets] = 51.2 KB

    const int lane = threadIdx.x;           // 0..63, one wave
    const int bid = blockIdx.x;
    const int ntiles = ncells / CPT;

    float acc = 0.0f;

    // Stage one tile (both tensors) into lbuf[b]: 24x w16 + 4x w4 chunks,
    // linear LDS (global_load_lds writes base + lane*width).
    auto stage = [&](int b, int t) {
        const float* ps = preds + (long long)t * TILE_F;
        const float* ts = targets + (long long)t * TILE_F;
        float* lp = lbuf[b];
        float* lt = lbuf[b] + TILE_F;
        #pragma unroll
        for (int c = 0; c < 12; ++c)
            __builtin_amdgcn_global_load_lds((gvoid_t*)(ps + c * 256 + lane * 4),
                                             (lvoid_t*)(lp + c * 256), 16, 0, 0);
        #pragma unroll
        for (int c = 0; c < 2; ++c)
            __builtin_amdgcn_global_load_lds((gvoid_t*)(ps + 3072 + c * 64 + lane),
                                             (lvoid_t*)(lp + 3072 + c * 64), 4, 0, 0);
        #pragma unroll
        for (int c = 0; c < 12; ++c)
            __builtin_amdgcn_global_load_lds((gvoid_t*)(ts + c * 256 + lane * 4),
                                             (lvoid_t*)(lt + c * 256), 16, 0, 0);
        #pragma unroll
        for (int c = 0; c < 2; ++c)
            __builtin_amdgcn_global_load_lds((gvoid_t*)(ts + 3072 + c * 64 + lane),
                                             (lvoid_t*)(lt + 3072 + c * 64), 4, 0, 0);
    };

    // ---- software pipeline: prologue stage, counted-vmcnt steady state ----
    if (bid < ntiles) stage(0, bid);
    int b = 0;
    for (int t = bid; t < ntiles; t += nb) {
        const int tn = t + nb;
        if (tn < ntiles) {
            stage(b ^ 1, tn);
            // wait only for tile t's 28 loads; tn's 28 stay in flight
            asm volatile("s_waitcnt vmcnt(28)" ::: "memory");
        } else {
            asm volatile("s_waitcnt vmcnt(0)" ::: "memory");
        }
        __builtin_amdgcn_sched_barrier(0);

        const float2* cp2 = (const float2*)(lbuf[b] + lane * NPC);
        const float2* ct2 = (const float2*)(lbuf[b] + TILE_F + lane * NPC);
        acc += cell_loss(cp2, ct2);
        b ^= 1;
    }

    // ---- remainder cells (ncells % 64; zero for this problem size) ----
    const int rem0 = ntiles * CPT;
    if (rem0 < ncells && bid == nb - 1) {
        for (int i = rem0 + lane; i < ncells; i += TPB) {
            const float2* cp2 = (const float2*)(preds + (long long)i * NPC);
            const float2* ct2 = (const float2*)(targets + (long long)i * NPC);
            acc += cell_loss(cp2, ct2);
        }
    }

    // ---- wave reduction, one plain store per block (no atomics) ----
    #pragma unroll
    for (int off = 32; off >= 1; off >>= 1) acc += __shfl_down(acc, off);
    if (lane == 0) part[bid] = acc;
}

__global__ __launch_bounds__(256) void yolo_final_kernel(
        const float* __restrict__ part, float* __restrict__ out,
        int nblk, float invN) {
    __shared__ float wsum[4];
    const int tid = threadIdx.x;
    float s = 0.0f;
    for (int i = tid; i < nblk; i += 256) s += part[i];
    #pragma unroll
    for (int off = 32; off >= 1; off >>= 1) s += __shfl_down(s, off);
    if ((tid & 63) == 0) wsum[tid >> 6] = s;
    __syncthreads();
    if (tid == 0) {
        out[0] = (wsum[0] + wsum[1] + wsum[2] + wsum[3]) * invN;
    }
}

extern "C" void kernel_launch(void* const* d_in, const int* in_sizes, int n_in,
                              void* d_out, int out_size, void* d_ws, size_t ws_size,
                              hipStream_t stream) {
    const float* preds = (const float*)d_in[0];
    const float* targets = (const float*)d_in[1];
    float* out = (float*)d_out;
    float* part = (float*)d_ws;                 // nb floats of scratch

    const int ncells = in_sizes[0] / NPC;       // N*S*S = 401408
    const int N = ncells / 49;                  // S*S = 49
    const int nb = 768;                          // 3 blocks/CU x 256 CU

    yolo_cell_kernel<<<nb, TPB, 0, stream>>>(preds, targets, part, ncells, nb);
    yolo_final_kernel<<<1, 256, 0, stream>>>(part, out, nb, 1.0f / (float)N);
}